// Round 1
// baseline (99.825 us; speedup 1.0000x reference)
//
#include <hip/hip_runtime.h>

#define GS   7
#define CCH  490
#define HH   128
#define WW   128
#define LDW  132        // padded LDS row stride (floats): +4 keeps b128 16B-aligned,
                        // conflict-free b128 row access and free b32 col access
#define HWSZ (HH * WW)

// lgkm-only barrier: makes LDS writes visible across waves WITHOUT draining vmcnt,
// so the batch-1 register prefetch stays in flight across phases B + pool.
// ("memory" clobber pins all ds/global ops on the correct side of the barrier.)
__device__ __forceinline__ void bar_lds() {
    asm volatile("s_waitcnt lgkmcnt(0)" ::: "memory");
    __builtin_amdgcn_s_barrier();
}

__global__ __launch_bounds__(512, 4) void psroi_fused(
    const float* __restrict__ rois,
    const float* __restrict__ feat,
    const int*   __restrict__ stride_p,
    float*       __restrict__ out)
{
#pragma clang fp contract(off)
    __shared__ float S[HH * LDW];   // 67,584 B -> 2 blocks/CU

    const int c   = blockIdx.x;     // channel within batch, 0..489; block does BOTH batches
    const int tid = threadIdx.x;

    const int col = tid & 127;      // phase-A mapping: wave = 64 consecutive cols, same seg
    const int seg = tid >> 7;       // 0..3
    const int r0  = seg * 32;

    const float* __restrict__ f0 = feat + (size_t)c * HWSZ;           // (b=0, c)
    const float* __restrict__ f1 = feat + (size_t)(CCH + c) * HWSZ;   // (b=1, c)

    // ---- issue batch-0 feature loads first (longest latency), coalesced 256B/wave-instr
    float v[32];
    {
        const float* fp = f0 + r0 * WW + col;
        #pragma unroll
        for (int i = 0; i < 32; ++i)
            v[i] = fp[i * WW];
    }

    // ---- per-thread ROI geometry: identical for both batches (same c) -> compute ONCE.
    // Exact reference op order, fp32, no contraction (bit-identical to previous kernel).
    const int n = tid;              // 512 threads == 512 rois
    const float b_f = rois[n * 5 + 0];
    const int   bi  = (int)b_f;
    const float ss  = 1.0f / (float)(*stride_p);
    const int d   = c / (GS * GS);
    const int rem = c - d * (GS * GS);
    const int pi  = rem / GS;
    const int pj  = rem - pi * GS;

    const float x1 = rois[n * 5 + 1];
    const float y1 = rois[n * 5 + 2];
    const float x2 = rois[n * 5 + 3];
    const float y2 = rois[n * 5 + 4];

    float rsw = rintf(x1) * ss;
    float rsh = rintf(y1) * ss;
    float rew = (rintf(x2) + 1.0f) * ss;
    float reh = (rintf(y2) + 1.0f) * ss;
    float rwv = rew - rsw;
    float rhv = reh - rsh;
    float rwm = rwv * 1.3f;
    float rhm = rhv * 1.3f;
    float swm = (rsw + rew) * 0.5f - rwm * 0.5f;
    float shm = (rsh + reh) * 0.5f - rhm * 0.5f;
    rwm = fmaxf(rwm, 0.1f);
    rhm = fmaxf(rhm, 0.1f);
    float bin_h = rhm / 7.0f;
    float bin_w = rwm / 7.0f;
    float dh = bin_h * 0.25f;
    float dw = bin_w * 0.25f;

    const float gi = (float)pi;
    const float gj = (float)pj;
    const int hs  = (int)fminf(fmaxf(floorf(shm + gi * bin_h - dh),          0.0f), 128.0f);
    const int he  = (int)fminf(fmaxf(ceilf (shm + (gi + 1.0f) * bin_h + dh), 0.0f), 128.0f);
    const int ws2 = (int)fminf(fmaxf(floorf(swm + gj * bin_w - dw),          0.0f), 128.0f);
    const int we  = (int)fminf(fmaxf(ceilf (swm + (gj + 1.0f) * bin_w + dw), 0.0f), 128.0f);
    const int area = (he - hs) * (we - ws2);

    // ---- Phase B: cumsum over W. thread = (row, 32-col seg); quads share a row.
    auto phaseB = [&]() {
#pragma clang fp contract(off)
        const int row = tid >> 2;       // wave = 16 rows x 4 col-segs
        const int ws_ = tid & 3;
        float* rp = &S[row * LDW + ws_ * 32];

        float u[32];
        #pragma unroll
        for (int i = 0; i < 8; ++i) {   // 8x ds_read_b128, imm offsets
            const float4 q = *(const float4*)&rp[i * 4];
            u[4 * i + 0] = q.x; u[4 * i + 1] = q.y;
            u[4 * i + 2] = q.z; u[4 * i + 3] = q.w;
        }
        #pragma unroll
        for (int i = 1; i < 32; ++i)
            u[i] += u[i - 1];

        const float tot = u[31];        // cross-seg fixup: 3 shuffles within quad
        const float t1 = __shfl_up(tot, 1, 64);
        const float t2 = __shfl_up(tot, 2, 64);
        const float t3 = __shfl_up(tot, 3, 64);
        float off2 = 0.0f;
        if (ws_ > 0) off2 += t1;
        if (ws_ > 1) off2 += t2;
        if (ws_ > 2) off2 += t3;

        #pragma unroll
        for (int i = 0; i < 8; ++i) {   // 8x ds_write_b128 in place
            float4 q;
            q.x = u[4 * i + 0] + off2; q.y = u[4 * i + 1] + off2;
            q.z = u[4 * i + 2] + off2; q.w = u[4 * i + 3] + off2;
            *(float4*)&rp[i * 4] = q;
        }
    };

    auto pool = [&](int bsel) {
#pragma clang fp contract(off)
        if (bi == bsel) {
            const float A  = (he > 0 && we  > 0) ? S[(he - 1) * LDW + (we  - 1)] : 0.0f;
            const float Bv = (hs > 0 && we  > 0) ? S[(hs - 1) * LDW + (we  - 1)] : 0.0f;
            const float Cv = (he > 0 && ws2 > 0) ? S[(he - 1) * LDW + (ws2 - 1)] : 0.0f;
            const float Dv = (hs > 0 && ws2 > 0) ? S[(hs - 1) * LDW + (ws2 - 1)] : 0.0f;
            const float total = ((A - Bv) - Cv) + Dv;   // reference order
            out[(size_t)n * CCH + c] = (area > 0) ? (total / (float)area) : 0.0f;
        }
    };

    // =========================== batch 0 ===========================
    #pragma unroll
    for (int i = 1; i < 32; ++i) v[i] += v[i - 1];      // serial register scan over H
    S[seg * LDW + col] = v[31];                         // seg-total exchange rows 0..3
    bar_lds();
    {
        float off = 0.0f;                               // seg uniform per wave
        if (seg > 0) off += S[0 * LDW + col];
        if (seg > 1) off += S[1 * LDW + col];
        if (seg > 2) off += S[2 * LDW + col];
        bar_lds();
        float* sp = &S[r0 * LDW + col];
        #pragma unroll
        for (int i = 0; i < 32; ++i)                    // imm-offset ds_write_b32
            sp[i * LDW] = v[i] + off;
    }
    // ---- prefetch batch 1 into v[] (dead after the LDS write above).
    // vmcnt stays outstanding across the lgkm-only barriers: HBM stays busy
    // under phase B + pooling instead of idling.
    {
        const float* fp = f1 + r0 * WW + col;
        #pragma unroll
        for (int i = 0; i < 32; ++i)
            v[i] = fp[i * WW];
    }
    bar_lds();          // phase-A writes visible
    phaseB();
    bar_lds();          // phase-B writes visible
    pool(0);
    bar_lds();          // pool reads complete before batch-1 overwrites S

    // =========================== batch 1 ===========================
    #pragma unroll
    for (int i = 1; i < 32; ++i) v[i] += v[i - 1];      // compiler waits vmcnt here
    S[seg * LDW + col] = v[31];
    bar_lds();
    {
        float off = 0.0f;
        if (seg > 0) off += S[0 * LDW + col];
        if (seg > 1) off += S[1 * LDW + col];
        if (seg > 2) off += S[2 * LDW + col];
        bar_lds();
        float* sp = &S[r0 * LDW + col];
        #pragma unroll
        for (int i = 0; i < 32; ++i)
            sp[i * LDW] = v[i] + off;
    }
    bar_lds();
    phaseB();
    bar_lds();
    pool(1);
}

extern "C" void kernel_launch(void* const* d_in, const int* in_sizes, int n_in,
                              void* d_out, int out_size, void* d_ws, size_t ws_size,
                              hipStream_t stream)
{
    const float* rois     = (const float*)d_in[0];
    const float* feat     = (const float*)d_in[1];
    const int*   stride_p = (const int*)d_in[2];
    float*       out      = (float*)d_out;

    dim3 grid(CCH);    // one workgroup per channel; each handles both batches (pipelined)
    dim3 block(512);
    hipLaunchKernelGGL(psroi_fused, grid, block, 0, stream, rois, feat, stride_p, out);
}